// Round 15
// baseline (351.303 us; speedup 1.0000x reference)
//
#include <hip/hip_runtime.h>
#include <hip/hip_bf16.h>
#include <math.h>

// ---------------- problem constants ----------------
#define BATCH  64
#define EMB    128
#define HID    512
#define TK     400
#define VOCAB  50000
#define MAX_OOV 100
#define VEXT   50100  // VOCAB + MAX_OOV
#define H2     1024   // 2*HID
#define K_RI   512    // 2*DSEM

// MFMA fragment types (cdna_hip_programming.md §3)
typedef short  bf16x8 __attribute__((ext_vector_type(8)));   // 8 bf16 in 4 VGPRs
typedef float  f32x4  __attribute__((ext_vector_type(4)));
typedef unsigned short u16x8 __attribute__((ext_vector_type(8)));

__device__ __forceinline__ unsigned short f2b(float f){
  unsigned u = __float_as_uint(f);
  u += 0x7fffu + ((u >> 16) & 1u);   // RNE f32 -> bf16
  return (unsigned short)(u >> 16);
}
__device__ __forceinline__ float sigm(float x){ return 1.0f/(1.0f+expf(-x)); }
__device__ __forceinline__ float clampf(float x, float lo, float hi){ return fminf(fmaxf(x, lo), hi); }
// fast tanh via v_exp_f32: exact saturation, ~1e-6 abs err
__device__ __forceinline__ float fast_tanh(float x){
  float e = __expf(2.f*x);
  return 1.f - 2.f/(e + 1.f);
}
__device__ __forceinline__ bf16x8 ld_frag(const unsigned short* p){
  return __builtin_bit_cast(bf16x8, *(const u16x8*)p);
}
// pack 8 consecutive f32 -> 8 bf16
__device__ __forceinline__ u16x8 cvt8(const float4 a, const float4 b){
  u16x8 r;
  r[0]=f2b(a.x); r[1]=f2b(a.y); r[2]=f2b(a.z); r[3]=f2b(a.w);
  r[4]=f2b(b.x); r[5]=f2b(b.y); r[6]=f2b(b.z); r[7]=f2b(b.w);
  return r;
}

// ---------------- workspace layout (float offsets) ---------------- 1.56 MB total
#define WS_X        0          // 64*128
#define WS_H        8192       // 64*512
#define WS_STHAT    73728      // 64*1024
#define WS_DECFEA   139264     // 64*1024
#define WS_SCORES   204800     // 64*400
#define WS_SCORES2  230400     // 64*400 (fully overwritten by k_scores)
#define WS_ATTN     256000     // 64*400
#define WS_ASTRUCT  281600     // 64*400
#define WS_CSTRUCT  307200     // 64*1024
#define WS_PGEN     372736     // 64
#define WS_OUT1BF   372800     // 64*512 bf16 staged == 8192 floats used
#define WS_ROWMAX   389184     // 64
#define WS_ROWSUM   389248     // 64
// reuse (dead after k_softmax): vocab-softmax partials
#define WS_PMAX     WS_SCORES          // 64*8
#define WS_PSUM     (WS_SCORES+512)    // 64*8

// ---------------- output layout (f32 elements) ----------------
#define OUT_FINAL 0
#define OUT_H     3206400
#define OUT_C     3239168
#define OUT_CT    3271936
#define OUT_ATTN  3337472
#define OUT_PGEN  3363072
#define OUT_COV   3363136
// Scratch inside OUT_FINAL region (all dead before k_o2/k_vsm_write overwrite it):
//   gates:   out[0 .. 131072)                  (k_gates -> k_lstmpt)
//   Wr16f:   out[131072 .. 393216)             (k_wrcvt -> k_scores)
//   ctx partials: out[0 .. 524288)             (k_context -> k_ctxpgen; after scores)
#define OUT_WR16  131072
#define CTX_CT    0        // [4][64][1024]
#define CTX_CS    262144   // [4][64][1024]

// K0: one-time f32 -> bf16 conversion of Wr (1024x512) into FRAGMENT-MAJOR order:
// element (nb, f, lane, j) at WrF[(nb*16 + f)*512 + lane*8 + j] holds
// Wr[row = nb*16 + (lane&15)][k = f*32 + (lane>>4)*8 + j]  -- a wave's B-fragment
// load is ONE contiguous 1KB transaction, and the whole array is LINEAR so
// global_load_lds staging works with a linear LDS destination.
__global__ __launch_bounds__(256) void k_wrcvt(const float* __restrict__ Wr,
    unsigned short* __restrict__ WrF){
  int t = blockIdx.x*256 + threadIdx.x;      // 65536 threads
  int lane = t & 63;
  int f    = (t >> 6) & 15;
  int nb   = t >> 10;                        // 0..63
  int r  = nb*16 + (lane & 15);
  int k0 = f*32 + (lane >> 4)*8;
  const float4* p = (const float4*)(Wr + (size_t)r*512 + k0);
  *(u16x8*)(WrF + (size_t)t*8) = cvt8(p[0], p[1]);
}

// K1a: embedding gather + xc linear -> x  (wave-per-output, lane-split-K, coalesced)
__global__ __launch_bounds__(256) void k_embx(
    const int* __restrict__ y, const float* __restrict__ embW,
    const float* __restrict__ ct1, const float* __restrict__ xcW,
    const float* __restrict__ xcb, float* __restrict__ ws)
{
  __shared__ float vec[1152];
  int b = blockIdx.x, q = blockIdx.y, tid = threadIdx.x;
  int yb = y[b];
  for (int i = tid; i < 1024; i += 256) vec[i] = ct1[b*1024+i];
  if (tid < 128) vec[1024+tid] = embW[(size_t)yb*128+tid];
  __syncthreads();
  int wave = tid>>6, lane = tid&63;
  #pragma unroll 2
  for (int oo = 0; oo < 8; ++oo){
    int o = q*32 + wave*8 + oo;
    const float* row = xcW + (size_t)o*1152;
    float acc = 0.f;
    #pragma unroll
    for (int i=0;i<18;i++) acc += row[lane + 64*i] * vec[lane + 64*i];
    for (int off=32; off>0; off>>=1) acc += __shfl_down(acc, off);
    if (lane==0) ws[WS_X + b*128 + o] = xcb[o] + acc;
  }
}

// K1b: gates[b,g] = x[b]·Wih[g] + h0[b]·Whh[g] + bih[g] + bhh[g]
__global__ __launch_bounds__(256) void k_gates(
    const float* __restrict__ Wih, const float* __restrict__ Whh,
    const float* __restrict__ bih, const float* __restrict__ bhh,
    const float* __restrict__ sh, const float* __restrict__ ws,
    float* __restrict__ gates)
{
  __shared__ float xh[640];
  int b = blockIdx.x, gc = blockIdx.y, tid = threadIdx.x;
  for (int i=tid;i<128;i+=256) xh[i] = ws[WS_X + b*128 + i];
  for (int i=tid;i<512;i+=256) xh[128+i] = sh[b*512+i];
  __syncthreads();
  int wave = tid>>6, lane = tid&63;
  int gbase = gc*128 + wave*32;
  for (int gg=0; gg<32; ++gg){
    int g = gbase + gg;
    const float* ri = Wih + (size_t)g*128;
    const float* rh = Whh + (size_t)g*512;
    float acc = ri[lane]*xh[lane] + ri[lane+64]*xh[lane+64];
    #pragma unroll
    for (int i=0;i<8;i++) acc += rh[lane + 64*i] * xh[128 + lane + 64*i];
    for (int off=32; off>0; off>>=1) acc += __shfl_down(acc, off);
    if (lane==0) gates[b*2048 + g] = acc + bih[g] + bhh[g];
  }
}

// K1c: pointwise LSTM epilogue
__global__ __launch_bounds__(256) void k_lstmpt(
    const float* __restrict__ gates, const float* __restrict__ sc,
    float* __restrict__ ws, float* __restrict__ outh, float* __restrict__ outc)
{
  int b = blockIdx.x, tid = threadIdx.x;
  const float* g = gates + b*2048;
  for (int j = tid; j < 512; j += 256){
    float ig = sigm(g[j]),       fg = sigm(g[512+j]);
    float gg = tanhf(g[1024+j]), og = sigm(g[1536+j]);
    float c0 = sc[b*512+j];
    float cn = fg*c0 + ig*gg;
    float hn = og*tanhf(cn);
    ws[WS_H + b*512+j] = hn;
    ws[WS_STHAT + b*1024 + j] = hn; ws[WS_STHAT + b*1024 + 512 + j] = cn;
    outh[b*512+j] = hn; outc[b*512+j] = cn;
  }
}

// K2: dec_fea = s_t_hat @ Ws_W.T + Ws_b  (wave-per-output, lane-split-K, coalesced)
__global__ __launch_bounds__(256) void k_decfea(const float* __restrict__ WsW,
    const float* __restrict__ Wsb, float* __restrict__ ws){
  __shared__ float st[1024];
  int b = blockIdx.x, q = blockIdx.y, tid = threadIdx.x;
  for (int i=tid;i<1024;i+=256) st[i] = ws[WS_STHAT + b*1024 + i];
  __syncthreads();
  int wave = tid>>6, lane = tid&63;
  for (int oo=0; oo<64; ++oo){
    int n = q*256 + wave*64 + oo;
    const float* row = WsW + (size_t)n*1024;
    float acc = 0.f;
    #pragma unroll
    for (int i=0;i<16;i++) acc += row[lane + 64*i] * st[lane + 64*i];
    for (int off=32; off>0; off>>=1) acc += __shfl_down(acc, off);
    if (lane==0) ws[WS_DECFEA + b*1024 + n] = Wsb[n] + acc;
  }
}

// K34: FUSED scores kernel. grid 3400 x 512 threads.
//  blockIdx < 200  : scores2 path (frozen structure: 8 waves, shared-B
//                    double-buffered LDS, A-in-regs, ~80us) -- dispatched first.
//  blockIdx >= 200 : scores1 path, LDS-FREE: per-lane df/vv/wc/ef reads are
//                    contiguous 64B/lane (coalesced 4KB/wave); vv/wc/df L2-hot.
//                    (Old LDS version had a 32-way bank conflict: 3.7M cycles.)
// Both depend only on decfea; they write disjoint ws regions.
__global__ __launch_bounds__(512) void k_scores(const float* __restrict__ ri,
    const unsigned short* __restrict__ WrF, const float* __restrict__ vW,
    const float* __restrict__ ef, const float* __restrict__ cov,
    const float* __restrict__ WcW, float* __restrict__ ws){
  __shared__ __align__(16) unsigned char smem[65536];
  int tid = threadIdx.x, lane = tid & 63, w = tid >> 6;

  if (blockIdx.x < 200){
    // ---------------- scores2 path ----------------
    unsigned short (*Bs)[16384] = (unsigned short (*)[16384])smem;  // 2 x 32KB
    int m0 = blockIdx.x*128 + w*16;
    int fr = lane & 15, fq8 = (lane >> 4)*8;
    int cq = lane >> 4, cr = lane & 15;

    bf16x8 a[16];
    {
      const float* p = ri + (size_t)(m0 + fr)*K_RI + fq8;
      #pragma unroll
      for (int f=0; f<16; f++){
        float4 x0 = *(const float4*)(p + f*32);
        float4 x1 = *(const float4*)(p + f*32 + 4);
        a[f] = __builtin_bit_cast(bf16x8, cvt8(x0, x1));
      }
    }
    const float* decfea = ws + WS_DECFEA;
    int dfo[4];
    #pragma unroll
    for (int rg=0; rg<4; rg++) dfo[rg] = ((m0 + cq*4 + rg)/400)*1024;
    float sa[4] = {0.f,0.f,0.f,0.f};

    #pragma unroll
    for (int i=0;i<4;i++){
      int e = (i*512 + tid)*8;
      __builtin_amdgcn_global_load_lds(
        (const __attribute__((address_space(1))) unsigned int*)(WrF + e),
        (__attribute__((address_space(3))) unsigned int*)&Bs[0][e], 16, 0, 0);
    }
    for (int p=0; p<32; ++p){
      __syncthreads();
      if (p < 31){
        const unsigned short* src = WrF + (size_t)(p+1)*16384;
        unsigned short* dst = Bs[(p+1)&1];
        #pragma unroll
        for (int i=0;i<4;i++){
          int e = (i*512 + tid)*8;
          __builtin_amdgcn_global_load_lds(
            (const __attribute__((address_space(1))) unsigned int*)(src + e),
            (__attribute__((address_space(3))) unsigned int*)(dst + e), 16, 0, 0);
        }
      }
      const unsigned short* b0 = &Bs[p&1][lane*8];
      const unsigned short* b1 = b0 + 8192;
      f32x4 c0a={0.f,0.f,0.f,0.f}, c0b={0.f,0.f,0.f,0.f};
      f32x4 c1a={0.f,0.f,0.f,0.f}, c1b={0.f,0.f,0.f,0.f};
      #pragma unroll
      for (int f=0; f<16; f+=2){
        bf16x8 x0 = ld_frag(b0 + f*512), y0 = ld_frag(b0 + f*512 + 512);
        bf16x8 x1 = ld_frag(b1 + f*512), y1 = ld_frag(b1 + f*512 + 512);
        c0a = __builtin_amdgcn_mfma_f32_16x16x32_bf16(a[f],   x0, c0a, 0,0,0);
        c1a = __builtin_amdgcn_mfma_f32_16x16x32_bf16(a[f],   x1, c1a, 0,0,0);
        c0b = __builtin_amdgcn_mfma_f32_16x16x32_bf16(a[f+1], y0, c0b, 0,0,0);
        c1b = __builtin_amdgcn_mfma_f32_16x16x32_bf16(a[f+1], y1, c1b, 0,0,0);
      }
      int col0 = p*32 + cr, col1 = col0 + 16;
      float v0 = vW[col0], v1 = vW[col1];
      #pragma unroll
      for (int rg=0; rg<4; rg++){
        float t0 = c0a[rg] + c0b[rg] + decfea[dfo[rg] + col0];
        float t1 = c1a[rg] + c1b[rg] + decfea[dfo[rg] + col1];
        sa[rg] += fast_tanh(t0)*v0 + fast_tanh(t1)*v1;
      }
    }
    #pragma unroll
    for (int rg=0; rg<4; rg++){
      float v = sa[rg];
      v += __shfl_xor(v, 1); v += __shfl_xor(v, 2);
      v += __shfl_xor(v, 4); v += __shfl_xor(v, 8);
      sa[rg] = v;
    }
    if (cr == 0){
      #pragma unroll
      for (int rg=0; rg<4; rg++)
        ws[WS_SCORES2 + m0 + cq*4 + rg] = clampf(sa[rg], -64.f, 64.f);
    }
  } else {
    // ---------------- scores1 path (LDS-free) ----------------
    int sb = blockIdx.x - 200;
    int b = sb / 50, tq = sb % 50;
    int t = tq*8 + w;
    float cv = cov[b*400+t];
    int base = lane*16;
    const float4* e = (const float4*)(ef + (size_t)(b*400+t)*1024 + base);
    float4 e0=e[0], e1=e[1], e2=e[2], e3=e[3];
    const float4* dp = (const float4*)(ws + WS_DECFEA + b*1024 + base);
    float4 d0=dp[0], d1=dp[1], d2=dp[2], d3=dp[3];
    const float4* vp = (const float4*)(vW + base);
    float4 v0=vp[0], v1=vp[1], v2=vp[2], v3=vp[3];
    const float4* wp = (const float4*)(WcW + base);
    float4 w0=wp[0], w1=wp[1], w2=wp[2], w3=wp[3];
    float ebuf[16] = {e0.x,e0.y,e0.z,e0.w, e1.x,e1.y,e1.z,e1.w,
                      e2.x,e2.y,e2.z,e2.w, e3.x,e3.y,e3.z,e3.w};
    float dbuf[16] = {d0.x,d0.y,d0.z,d0.w, d1.x,d1.y,d1.z,d1.w,
                      d2.x,d2.y,d2.z,d2.w, d3.x,d3.y,d3.z,d3.w};
    float vbuf[16] = {v0.x,v0.y,v0.z,v0.w, v1.x,v1.y,v1.z,v1.w,
                      v2.x,v2.y,v2.z,v2.w, v3.x,v3.y,v3.z,v3.w};
    float wbuf[16] = {w0.x,w0.y,w0.z,w0.w, w1.x,w1.y,w1.z,w1.w,
                      w2.x,w2.y,w2.z,w2.w, w3.x,w3.y,w3.z,w3.w};
    float acc = 0.f;
    #pragma unroll
    for (int j=0;j<16;j++)
      acc += fast_tanh(ebuf[j] + dbuf[j] + cv*wbuf[j]) * vbuf[j];
    for (int off=32; off>0; off>>=1) acc += __shfl_down(acc, off, 64);
    if (lane==0) ws[WS_SCORES + b*400 + t] = clampf(acc, -64.f, 64.f);
  }
}

// K5: both softmaxes over t
__global__ __launch_bounds__(256) void k_softmax(const float* __restrict__ mask,
    const float* __restrict__ covin, float* __restrict__ ws,
    float* __restrict__ out){
  __shared__ float s1[400], s2[400], mk[400], red[256];
  int b = blockIdx.x, tid = threadIdx.x;
  for (int i=tid;i<400;i+=256){
    s1[i]=ws[WS_SCORES+b*400+i]; s2[i]=ws[WS_SCORES2+b*400+i]; mk[i]=mask[b*400+i];
  }
  __syncthreads();
  float lm = -1e30f;
  for (int i=tid;i<400;i+=256) lm = fmaxf(lm, s1[i]);
  red[tid]=lm; __syncthreads();
  for (int off=128;off>0;off>>=1){ if (tid<off) red[tid]=fmaxf(red[tid],red[tid+off]); __syncthreads(); }
  float mx1 = red[0]; __syncthreads();
  float ls=0.f;
  for (int i=tid;i<400;i+=256){ float e=__expf(s1[i]-mx1); s1[i]=e; ls+=e; }
  red[tid]=ls; __syncthreads();
  for (int off=128;off>0;off>>=1){ if (tid<off) red[tid]+=red[tid+off]; __syncthreads(); }
  float sum1 = red[0]; __syncthreads();
  float la=0.f;
  for (int i=tid;i<400;i+=256){ float a=(s1[i]/sum1)*mk[i]; s1[i]=a; la+=a; }
  red[tid]=la; __syncthreads();
  for (int off=128;off>0;off>>=1){ if (tid<off) red[tid]+=red[tid+off]; __syncthreads(); }
  float sumA = red[0]; __syncthreads();
  for (int i=tid;i<400;i+=256){
    float attn = s1[i]/sumA;
    ws[WS_ATTN + b*400 + i] = attn;
    out[OUT_ATTN + b*400 + i] = attn;
    out[OUT_COV  + b*400 + i] = covin[b*400+i] + attn;
  }
  float lm2 = -1e30f;
  for (int i=tid;i<400;i+=256) lm2 = fmaxf(lm2, s2[i]);
  red[tid]=lm2; __syncthreads();
  for (int off=128;off>0;off>>=1){ if (tid<off) red[tid]=fmaxf(red[tid],red[tid+off]); __syncthreads(); }
  float mx2 = red[0]; __syncthreads();
  float ls2=0.f;
  for (int i=tid;i<400;i+=256){ float e=__expf(s2[i]-mx2); s2[i]=e; ls2+=e; }
  red[tid]=ls2; __syncthreads();
  for (int off=128;off>0;off>>=1){ if (tid<off) red[tid]+=red[tid+off]; __syncthreads(); }
  float sum2 = red[0]; __syncthreads();
  for (int i=tid;i<400;i+=256) ws[WS_ASTRUCT + b*400 + i] = (s2[i]/sum2)*mk[i];
}

// K6: context partials, t-split x4 for memory-level parallelism. grid (64,4,4).
__global__ __launch_bounds__(256) void k_context(const float* __restrict__ eo,
    const float* __restrict__ ws, float* __restrict__ outp){
  __shared__ float at[100], as2[100];
  int b = blockIdx.x, tid = threadIdx.x;
  int n = blockIdx.y*256 + tid;
  int tz = blockIdx.z;
  for (int i=tid;i<100;i+=256){
    at[i]  = ws[WS_ATTN    + b*400 + tz*100 + i];
    as2[i] = ws[WS_ASTRUCT + b*400 + tz*100 + i];
  }
  __syncthreads();
  const float* p = eo + (size_t)b*400*1024 + (size_t)tz*100*1024 + n;
  float a1=0.f, a2=0.f;
  #pragma unroll 4
  for (int t=0;t<100;t++){
    float e = p[(size_t)t*1024];
    a1 += at[t]*e; a2 += as2[t]*e;
  }
  outp[CTX_CT + tz*65536 + b*1024 + n] = a1;
  outp[CTX_CS + tz*65536 + b*1024 + n] = a2;
}

// K6b+K7 fused: combine the 4 t-partials -> c_t (out), c_struct (ws), AND
// p_gen = sigmoid(pg_W . [c_struct, s_t_hat, x] + pg_b) using the just-summed
// c_struct registers (no global re-read of c_struct).
__global__ __launch_bounds__(256) void k_ctxpgen(const float* __restrict__ pgW,
    const float* __restrict__ pgb, float* __restrict__ ws,
    float* __restrict__ out){
  __shared__ float red[256];
  int b = blockIdx.x, tid = threadIdx.x;
  int n = tid*4;
  float4 ct = {0.f,0.f,0.f,0.f}, cs = {0.f,0.f,0.f,0.f};
  #pragma unroll
  for (int tz=0;tz<4;tz++){
    float4 a = *(const float4*)(out + CTX_CT + tz*65536 + b*1024 + n);
    float4 c = *(const float4*)(out + CTX_CS + tz*65536 + b*1024 + n);
    ct.x+=a.x; ct.y+=a.y; ct.z+=a.z; ct.w+=a.w;
    cs.x+=c.x; cs.y+=c.y; cs.z+=c.z; cs.w+=c.w;
  }
  *(float4*)(out + OUT_CT + b*1024 + n) = ct;
  *(float4*)(ws + WS_CSTRUCT + b*1024 + n) = cs;
  // pgen partial dot
  float4 pw = *(const float4*)(pgW + n);
  float a = cs.x*pw.x + cs.y*pw.y + cs.z*pw.z + cs.w*pw.w;
  float4 st = *(const float4*)(ws + WS_STHAT + b*1024 + n);
  float4 pw2 = *(const float4*)(pgW + 1024 + n);
  a += st.x*pw2.x + st.y*pw2.y + st.z*pw2.z + st.w*pw2.w;
  if (tid < 32){
    float4 xv = *(const float4*)(ws + WS_X + b*128 + tid*4);
    float4 pw3 = *(const float4*)(pgW + 2048 + tid*4);
    a += xv.x*pw3.x + xv.y*pw3.y + xv.z*pw3.z + xv.w*pw3.w;
  }
  red[tid]=a; __syncthreads();
  for (int off=128;off>0;off>>=1){ if(tid<off) red[tid]+=red[tid+off]; __syncthreads(); }
  if (tid==0){
    float p = sigm(red[0] + pgb[0]);
    ws[WS_PGEN+b]=p; out[OUT_PGEN+b]=p;
  }
}

// K8: out1 = o1_W @ [h_new, c_struct] + o1_b  (wave-per-output, lane-split-K;
// stored bf16 for the o2 MFMA GEMM)
__global__ __launch_bounds__(256) void k_out1(const float* __restrict__ o1W,
    const float* __restrict__ o1b, float* __restrict__ ws){
  __shared__ float in1[1536];
  int b=blockIdx.x, q=blockIdx.y, tid=threadIdx.x;
  for (int i=tid;i<512;i+=256)  in1[i]     = ws[WS_H + b*512 + i];
  for (int i=tid;i<1024;i+=256) in1[512+i] = ws[WS_CSTRUCT + b*1024 + i];
  __syncthreads();
  int wave = tid>>6, lane = tid&63;
  for (int oo=0; oo<64; ++oo){
    int o = q*256 + wave*64 + oo;
    const float* row = o1W + (size_t)o*1536;
    float acc = 0.f;
    #pragma unroll
    for (int i=0;i<24;i++) acc += row[lane + 64*i] * in1[lane + 64*i];
    for (int off=32; off>0; off>>=1) acc += __shfl_down(acc, off);
    if (lane==0) ((unsigned short*)(ws + WS_OUT1BF))[b*512 + o] = f2b(o1b[o] + acc);
  }
}

// K9: logits = out1 @ o2_W.T + o2_b  (M=64, N=50000, K=512); f32 logits staged in d_out
__global__ __launch_bounds__(256) void k_o2(float* __restrict__ ws,
    const float* __restrict__ o2W, const float* __restrict__ o2b,
    float* __restrict__ out){
  __shared__ __align__(16) unsigned short As[64][72];
  __shared__ __align__(16) unsigned short Bs[64][72];
  int tid=threadIdx.x;
  int n0 = blockIdx.x*64;
  int lane=tid&63, wave=tid>>6, wm=wave&1, wn=wave>>1;
  int lrow=tid>>2, lcol=(tid&3)*16;
  const unsigned short* out1 = (const unsigned short*)(ws + WS_OUT1BF);
  f32x4 acc00={0.f,0.f,0.f,0.f}, acc01={0.f,0.f,0.f,0.f};
  f32x4 acc10={0.f,0.f,0.f,0.f}, acc11={0.f,0.f,0.f,0.f};
  int nrow = n0 + lrow;
  bool bvalid = nrow < VOCAB;
  int fr = lane & 15, fq = (lane >> 4) * 8;
  for (int kc=0;kc<512;kc+=64){
    u16x8 a0 = *(const u16x8*)(out1 + lrow*512 + kc + lcol);
    u16x8 a1 = *(const u16x8*)(out1 + lrow*512 + kc + lcol + 8);
    u16x8 bb0 = {0,0,0,0,0,0,0,0}, bb1 = {0,0,0,0,0,0,0,0};
    if (bvalid){
      const float4* bp = (const float4*)(o2W + (size_t)nrow*512 + kc + lcol);
      float4 b0=bp[0], b1=bp[1], b2=bp[2], b3=bp[3];
      bb0 = cvt8(b0,b1); bb1 = cvt8(b2,b3);
    }
    __syncthreads();
    *(u16x8*)&As[lrow][lcol] = a0;  *(u16x8*)&As[lrow][lcol+8] = a1;
    *(u16x8*)&Bs[lrow][lcol] = bb0; *(u16x8*)&Bs[lrow][lcol+8] = bb1;
    __syncthreads();
    #pragma unroll
    for (int kk=0; kk<64; kk+=32){
      bf16x8 aA = ld_frag(&As[wm*32 +      fr][kk + fq]);
      bf16x8 aB = ld_frag(&As[wm*32 + 16 + fr][kk + fq]);
      bf16x8 bA = ld_frag(&Bs[wn*32 +      fr][kk + fq]);
      bf16x8 bB = ld_frag(&Bs[wn*32 + 16 + fr][kk + fq]);
      acc00 = __builtin_amdgcn_mfma_f32_16x16x32_bf16(aA, bA, acc00, 0,0,0);
      acc01 = __builtin_amdgcn_mfma_f32_16x16x32_bf16(aA, bB, acc01, 0,0,0);
      acc10 = __builtin_amdgcn_mfma_f32_16x16x32_bf16(aB, bA, acc10, 0,0,0);
      acc11 = __builtin_amdgcn_mfma_f32_16x16x32_bf16(aB, bB, acc11, 0,0,0);
    }
  }
  int cq=lane>>4, cr=lane&15;
  #pragma unroll
  for (int i=0;i<2;i++){
    #pragma unroll
    for (int rg=0;rg<4;rg++){
      int row = wm*32 + i*16 + cq*4 + rg;   // batch row (0..63)
      int n1 = n0 + wn*32 + cr, n2 = n1+16;
      float v1 = (i==0?acc00[rg]:acc10[rg]);
      float v2 = (i==0?acc01[rg]:acc11[rg]);
      if (n1 < VOCAB) out[(size_t)row*VEXT + n1] = clampf(v1 + o2b[n1], -80.f, 80.f);
      if (n2 < VOCAB) out[(size_t)row*VEXT + n2] = clampf(v2 + o2b[n2], -80.f, 80.f);
    }
  }
}

// K10a: vocab-softmax stats, 8-way n-split. grid (64,8): partial max + expsum
// (local-max form) per 6250-elem slice -> ws partials.
__global__ __launch_bounds__(256) void k_vsm_part(const float* __restrict__ out,
    float* __restrict__ ws){
  __shared__ float red[256];
  int b=blockIdx.x, s=blockIdx.y, tid=threadIdx.x;
  const float* lg = out + (size_t)b*VEXT + s*6250;
  float lm=-1e30f;
  for (int i=tid;i<6250;i+=256) lm=fmaxf(lm, lg[i]);
  red[tid]=lm; __syncthreads();
  for (int off=128;off>0;off>>=1){ if(tid<off) red[tid]=fmaxf(red[tid],red[tid+off]); __syncthreads(); }
  float mx=red[0]; __syncthreads();
  float sm=0.f;
  for (int i=tid;i<6250;i+=256) sm+=__expf(lg[i]-mx);
  red[tid]=sm; __syncthreads();
  for (int off=128;off>0;off>>=1){ if(tid<off) red[tid]+=red[tid+off]; __syncthreads(); }
  if (tid==0){ ws[WS_PMAX + b*8 + s]=mx; ws[WS_PSUM + b*8 + s]=red[0]; }
}

// K10a': combine 8 partials per row -> (rowmax, rowsum) with rescale (exact)
__global__ __launch_bounds__(64) void k_vsm_comb(float* __restrict__ ws){
  int b = blockIdx.x;
  if (threadIdx.x==0){
    float M=-1e30f;
    for (int s=0;s<8;s++) M=fmaxf(M, ws[WS_PMAX + b*8 + s]);
    float S=0.f;
    for (int s=0;s<8;s++) S += __expf(ws[WS_PMAX + b*8 + s]-M)*ws[WS_PSUM + b*8 + s];
    ws[WS_ROWMAX+b]=M; ws[WS_ROWSUM+b]=S;
  }
}

// K10b: in-place  out <- p_gen * softmax(logits); zero the OOV tail
__global__ __launch_bounds__(256) void k_vsm_write(const float* __restrict__ ws,
    float* __restrict__ out){
  int b=blockIdx.y;
  int i=blockIdx.x*256+threadIdx.x;
  if (i>=VEXT) return;
  float* p = out + (size_t)b*VEXT + i;
  if (i<VOCAB) *p = ws[WS_PGEN+b]*__expf(*p - ws[WS_ROWMAX+b])/ws[WS_ROWSUM+b];
  else         *p = 0.f;
}

// K10c: scatter-add (1-p_gen)*attn at extended-vocab indices (plain f32 atomics)
__global__ __launch_bounds__(256) void k_scatter(const int* __restrict__ ebev,
    const float* __restrict__ ws, float* __restrict__ out){
  int idx = blockIdx.x*256+threadIdx.x;  // 25600 total
  int b = idx/400;
  float add = (1.f - ws[WS_PGEN+b]) * ws[WS_ATTN+idx];
  int v = ebev[idx];
  atomicAdd(out + (size_t)b*VEXT + v, add);
}

extern "C" void kernel_launch(void* const* d_in, const int* in_sizes, int n_in,
                              void* d_out, int out_size, void* d_ws, size_t ws_size,
                              hipStream_t stream){
  (void)in_sizes; (void)n_in; (void)out_size; (void)ws_size;
  const int*   y_t_1   = (const int*)d_in[0];
  const float* s_h     = (const float*)d_in[1];
  const float* s_c     = (const float*)d_in[2];
  const float* enc_out = (const float*)d_in[3];
  const float* enc_ft  = (const float*)d_in[4];
  const float* mask    = (const float*)d_in[5];
  const float* c_t_1   = (const float*)d_in[6];
  const int*   ebev    = (const int*)d_in[8];
  const float* cover   = (const float*)d_in[9];
  const float* ri      = (const float*)d_in[11];
  const float* embW    = (const float*)d_in[12];
  const float* WsW     = (const float*)d_in[13];
  const float* Wsb     = (const float*)d_in[14];
  const float* vW      = (const float*)d_in[15];
  const float* WcW     = (const float*)d_in[16];
  const float* WrW     = (const float*)d_in[17];
  const float* xcW     = (const float*)d_in[18];
  const float* xcb     = (const float*)d_in[19];
  const float* Wih     = (const float*)d_in[20];
  const float* Whh     = (const float*)d_in[21];
  const float* bih     = (const float*)d_in[22];
  const float* bhh     = (const float*)d_in[23];
  const float* pgW     = (const float*)d_in[24];
  const float* pgb     = (const float*)d_in[25];
  const float* o1W     = (const float*)d_in[26];
  const float* o1b     = (const float*)d_in[27];
  const float* o2W     = (const float*)d_in[28];
  const float* o2b     = (const float*)d_in[29];
  float* ws  = (float*)d_ws;
  float* out = (float*)d_out;
  float* gates = out;   // scratch inside OUT_FINAL region, overwritten by k_o2/k_vsm_write
  unsigned short* Wr16 = (unsigned short*)(out + OUT_WR16);

  k_wrcvt   <<<256,           256,0,stream>>>(WrW, Wr16);
  k_embx    <<<dim3(BATCH,4), 256,0,stream>>>(y_t_1, embW, c_t_1, xcW, xcb, ws);
  k_gates   <<<dim3(BATCH,16),256,0,stream>>>(Wih, Whh, bih, bhh, s_h, ws, gates);
  k_lstmpt  <<<BATCH,         256,0,stream>>>(gates, s_c, ws, out+OUT_H, out+OUT_C);
  k_decfea  <<<dim3(BATCH,4), 256,0,stream>>>(WsW, Wsb, ws);
  k_scores  <<<3400,          512,0,stream>>>(ri, Wr16, vW, enc_ft, cover, WcW, ws);
  k_softmax <<<BATCH,         256,0,stream>>>(mask, cover, ws, out);
  k_context <<<dim3(BATCH,4,4),256,0,stream>>>(enc_out, ws, out);
  k_ctxpgen <<<BATCH,         256,0,stream>>>(pgW, pgb, ws, out);
  k_out1    <<<dim3(BATCH,2), 256,0,stream>>>(o1W, o1b, ws);
  k_o2      <<<782,           256,0,stream>>>(ws, o2W, o2b, out);
  k_vsm_part<<<dim3(BATCH,8), 256,0,stream>>>(out, ws);
  k_vsm_comb<<<BATCH,         64, 0,stream>>>(ws);
  k_vsm_write<<<dim3(196,BATCH),256,0,stream>>>(ws, out);
  k_scatter <<<100,           256,0,stream>>>(ebev, ws, out);
}

// Round 16
// 335.696 us; speedup vs baseline: 1.0465x; 1.0465x over previous
//
#include <hip/hip_runtime.h>
#include <hip/hip_bf16.h>
#include <math.h>

// ---------------- problem constants ----------------
#define BATCH  64
#define EMB    128
#define HID    512
#define TK     400
#define VOCAB  50000
#define MAX_OOV 100
#define VEXT   50100  // VOCAB + MAX_OOV
#define H2     1024   // 2*HID
#define K_RI   512    // 2*DSEM

// MFMA fragment types (cdna_hip_programming.md §3)
typedef short  bf16x8 __attribute__((ext_vector_type(8)));   // 8 bf16 in 4 VGPRs
typedef float  f32x4  __attribute__((ext_vector_type(4)));
typedef unsigned short u16x8 __attribute__((ext_vector_type(8)));

__device__ __forceinline__ unsigned short f2b(float f){
  unsigned u = __float_as_uint(f);
  u += 0x7fffu + ((u >> 16) & 1u);   // RNE f32 -> bf16
  return (unsigned short)(u >> 16);
}
__device__ __forceinline__ float sigm(float x){ return 1.0f/(1.0f+expf(-x)); }
__device__ __forceinline__ float clampf(float x, float lo, float hi){ return fminf(fmaxf(x, lo), hi); }
// fast tanh via v_exp_f32: exact saturation, ~1e-6 abs err
__device__ __forceinline__ float fast_tanh(float x){
  float e = __expf(2.f*x);
  return 1.f - 2.f/(e + 1.f);
}
__device__ __forceinline__ bf16x8 ld_frag(const unsigned short* p){
  return __builtin_bit_cast(bf16x8, *(const u16x8*)p);
}
// pack 8 consecutive f32 -> 8 bf16
__device__ __forceinline__ u16x8 cvt8(const float4 a, const float4 b){
  u16x8 r;
  r[0]=f2b(a.x); r[1]=f2b(a.y); r[2]=f2b(a.z); r[3]=f2b(a.w);
  r[4]=f2b(b.x); r[5]=f2b(b.y); r[6]=f2b(b.z); r[7]=f2b(b.w);
  return r;
}

// ---------------- workspace layout (float offsets) ---------------- 1.56 MB total
#define WS_X        0          // 64*128
#define WS_H        8192       // 64*512
#define WS_STHAT    73728      // 64*1024
#define WS_DECFEA   139264     // 64*1024
#define WS_SCORES   204800     // 64*400
#define WS_SCORES2  230400     // 64*400 (fully overwritten by k_scores2)
#define WS_ATTN     256000     // 64*400
#define WS_ASTRUCT  281600     // 64*400
#define WS_CSTRUCT  307200     // 64*1024
#define WS_PGEN     372736     // 64
#define WS_OUT1BF   372800     // 64*512 bf16 staged == 8192 floats used
#define WS_ROWMAX   389184     // 64
#define WS_ROWSUM   389248     // 64
// reuse (dead after k_softmax): vocab-softmax partials
#define WS_PMAX     WS_SCORES          // 64*8
#define WS_PSUM     (WS_SCORES+512)    // 64*8

// ---------------- output layout (f32 elements) ----------------
#define OUT_FINAL 0
#define OUT_H     3206400
#define OUT_C     3239168
#define OUT_CT    3271936
#define OUT_ATTN  3337472
#define OUT_PGEN  3363072
#define OUT_COV   3363136
// Scratch inside OUT_FINAL region (all dead before k_o2/k_vsm_write overwrite it):
//   gates:   out[0 .. 131072)                  (k_gates -> k_lstmpt)
//   Wr16f:   out[131072 .. 393216)             (k_wrcvt -> k_scores2)
//   ctx partials: out[0 .. 524288)             (k_context -> k_ctxsum; after scores2)
#define OUT_WR16  131072
#define CTX_CT    0        // [4][64][1024]
#define CTX_CS    262144   // [4][64][1024]

// K0: one-time f32 -> bf16 conversion of Wr (1024x512) into FRAGMENT-MAJOR order:
// element (nb, f, lane, j) at WrF[(nb*16 + f)*512 + lane*8 + j] holds
// Wr[row = nb*16 + (lane&15)][k = f*32 + (lane>>4)*8 + j]  -- a wave's B-fragment
// load is ONE contiguous 1KB transaction, and the whole array is LINEAR so
// global_load_lds staging works with a linear LDS destination.
__global__ __launch_bounds__(256) void k_wrcvt(const float* __restrict__ Wr,
    unsigned short* __restrict__ WrF){
  int t = blockIdx.x*256 + threadIdx.x;      // 65536 threads
  int lane = t & 63;
  int f    = (t >> 6) & 15;
  int nb   = t >> 10;                        // 0..63
  int r  = nb*16 + (lane & 15);
  int k0 = f*32 + (lane >> 4)*8;
  const float4* p = (const float4*)(Wr + (size_t)r*512 + k0);
  *(u16x8*)(WrF + (size_t)t*8) = cvt8(p[0], p[1]);
}

// K1a: embedding gather + xc linear -> x  (wave-per-output, lane-split-K, coalesced)
__global__ __launch_bounds__(256) void k_embx(
    const int* __restrict__ y, const float* __restrict__ embW,
    const float* __restrict__ ct1, const float* __restrict__ xcW,
    const float* __restrict__ xcb, float* __restrict__ ws)
{
  __shared__ float vec[1152];
  int b = blockIdx.x, q = blockIdx.y, tid = threadIdx.x;
  int yb = y[b];
  for (int i = tid; i < 1024; i += 256) vec[i] = ct1[b*1024+i];
  if (tid < 128) vec[1024+tid] = embW[(size_t)yb*128+tid];
  __syncthreads();
  int wave = tid>>6, lane = tid&63;
  #pragma unroll 2
  for (int oo = 0; oo < 8; ++oo){
    int o = q*32 + wave*8 + oo;
    const float* row = xcW + (size_t)o*1152;
    float acc = 0.f;
    #pragma unroll
    for (int i=0;i<18;i++) acc += row[lane + 64*i] * vec[lane + 64*i];
    for (int off=32; off>0; off>>=1) acc += __shfl_down(acc, off);
    if (lane==0) ws[WS_X + b*128 + o] = xcb[o] + acc;
  }
}

// K1b: gates[b,g] = x[b]·Wih[g] + h0[b]·Whh[g] + bih[g] + bhh[g]
__global__ __launch_bounds__(256) void k_gates(
    const float* __restrict__ Wih, const float* __restrict__ Whh,
    const float* __restrict__ bih, const float* __restrict__ bhh,
    const float* __restrict__ sh, const float* __restrict__ ws,
    float* __restrict__ gates)
{
  __shared__ float xh[640];
  int b = blockIdx.x, gc = blockIdx.y, tid = threadIdx.x;
  for (int i=tid;i<128;i+=256) xh[i] = ws[WS_X + b*128 + i];
  for (int i=tid;i<512;i+=256) xh[128+i] = sh[b*512+i];
  __syncthreads();
  int wave = tid>>6, lane = tid&63;
  int gbase = gc*128 + wave*32;
  for (int gg=0; gg<32; ++gg){
    int g = gbase + gg;
    const float* ri = Wih + (size_t)g*128;
    const float* rh = Whh + (size_t)g*512;
    float acc = ri[lane]*xh[lane] + ri[lane+64]*xh[lane+64];
    #pragma unroll
    for (int i=0;i<8;i++) acc += rh[lane + 64*i] * xh[128 + lane + 64*i];
    for (int off=32; off>0; off>>=1) acc += __shfl_down(acc, off);
    if (lane==0) gates[b*2048 + g] = acc + bih[g] + bhh[g];
  }
}

// K1c: pointwise LSTM epilogue
__global__ __launch_bounds__(256) void k_lstmpt(
    const float* __restrict__ gates, const float* __restrict__ sc,
    float* __restrict__ ws, float* __restrict__ outh, float* __restrict__ outc)
{
  int b = blockIdx.x, tid = threadIdx.x;
  const float* g = gates + b*2048;
  for (int j = tid; j < 512; j += 256){
    float ig = sigm(g[j]),       fg = sigm(g[512+j]);
    float gg = tanhf(g[1024+j]), og = sigm(g[1536+j]);
    float c0 = sc[b*512+j];
    float cn = fg*c0 + ig*gg;
    float hn = og*tanhf(cn);
    ws[WS_H + b*512+j] = hn;
    ws[WS_STHAT + b*1024 + j] = hn; ws[WS_STHAT + b*1024 + 512 + j] = cn;
    outh[b*512+j] = hn; outc[b*512+j] = cn;
  }
}

// K2: dec_fea = s_t_hat @ Ws_W.T + Ws_b  (wave-per-output, lane-split-K, coalesced)
__global__ __launch_bounds__(256) void k_decfea(const float* __restrict__ WsW,
    const float* __restrict__ Wsb, float* __restrict__ ws){
  __shared__ float st[1024];
  int b = blockIdx.x, q = blockIdx.y, tid = threadIdx.x;
  for (int i=tid;i<1024;i+=256) st[i] = ws[WS_STHAT + b*1024 + i];
  __syncthreads();
  int wave = tid>>6, lane = tid&63;
  for (int oo=0; oo<64; ++oo){
    int n = q*256 + wave*64 + oo;
    const float* row = WsW + (size_t)n*1024;
    float acc = 0.f;
    #pragma unroll
    for (int i=0;i<16;i++) acc += row[lane + 64*i] * st[lane + 64*i];
    for (int off=32; off>0; off>>=1) acc += __shfl_down(acc, off);
    if (lane==0) ws[WS_DECFEA + b*1024 + n] = Wsb[n] + acc;
  }
}

// K3: scores1[b,t] = sum_n tanh(ef[b,t,n] + dec_fea[b,n] + cov[b,t]*Wc[n]) * v[n]
__global__ __launch_bounds__(256) void k_scores1(const float* __restrict__ ef,
    const float* __restrict__ cov, const float* __restrict__ vW,
    const float* __restrict__ WcW, float* __restrict__ ws){
  __shared__ float df[1024], vv[1024], wc[1024];
  int b = blockIdx.x, tid = threadIdx.x;
  for (int i=tid;i<1024;i+=256){ df[i]=ws[WS_DECFEA+b*1024+i]; vv[i]=vW[i]; wc[i]=WcW[i]; }
  __syncthreads();
  int wave = tid>>6, lane = tid&63;
  int t = blockIdx.y*4 + wave;
  float cv = cov[b*400+t];
  const float4* e = (const float4*)(ef + (size_t)(b*400+t)*1024 + lane*16);
  float4 e0 = e[0], e1 = e[1], e2 = e[2], e3 = e[3];
  float ebuf[16] = {e0.x,e0.y,e0.z,e0.w, e1.x,e1.y,e1.z,e1.w,
                    e2.x,e2.y,e2.z,e2.w, e3.x,e3.y,e3.z,e3.w};
  float acc = 0.f;
  int base = lane*16;
  #pragma unroll
  for (int j=0;j<16;j++){ int n=base+j; acc += fast_tanh(ebuf[j] + df[n] + cv*wc[n]) * vv[n]; }
  for (int off=32; off>0; off>>=1) acc += __shfl_down(acc, off, 64);
  if (lane==0) ws[WS_SCORES + b*400 + t] = clampf(acc, -64.f, 64.f);
}

// K4: fused att2 GEMM (M=25600,N=1024,K=512) + tanh*v row-reduction -> scores2.
// Shared-B wave-streaming: 400 blocks x 4 waves; each wave owns 16 m-rows
// (A in 64 VGPRs as bf16 frags). B is block-shared: double-buffered 32KB LDS
// tiles (2 n-blocks each) staged via global_load_lds width-16 from the LINEAR
// fragment-major Wr16f (linear dest == linear src, m104-safe). Stage for
// phase p+1 is issued right AFTER the barrier that opens phase p (T3-lite).
// L2 B-traffic: 1.6GB -> 400MB (4-way dedup). 32 barriers total. ~80us floor.
__global__ __launch_bounds__(256) void k_scores2(const float* __restrict__ ri,
    const unsigned short* __restrict__ WrF, const float* __restrict__ vW,
    float* __restrict__ ws){
  __shared__ __align__(16) unsigned short Bs[2][16384];   // 2 x 32KB
  int tid = threadIdx.x, lane = tid & 63, w = tid >> 6;
  int m0 = blockIdx.x*64 + w*16;
  int fr = lane & 15, fq8 = (lane >> 4)*8;   // A/B frag: row=lane&15, k=(lane>>4)*8+j
  int cq = lane >> 4, cr = lane & 15;        // C/D: row=(lane>>4)*4+reg, col=lane&15

  // ---- A: 16 rows x K=512 -> 16 bf16 fragments in registers (64 VGPR) ----
  bf16x8 a[16];
  {
    const float* p = ri + (size_t)(m0 + fr)*K_RI + fq8;
    #pragma unroll
    for (int f=0; f<16; f++){
      float4 x0 = *(const float4*)(p + f*32);
      float4 x1 = *(const float4*)(p + f*32 + 4);
      a[f] = __builtin_bit_cast(bf16x8, cvt8(x0, x1));
    }
  }

  const float* decfea = ws + WS_DECFEA;
  int dfo[4];
  #pragma unroll
  for (int rg=0; rg<4; rg++) dfo[rg] = ((m0 + cq*4 + rg)/400)*1024;
  float sa[4] = {0.f,0.f,0.f,0.f};

  // ---- prologue: stage phase 0 (32KB = 8 issues x 256 threads x 16B) ----
  #pragma unroll
  for (int i=0;i<8;i++){
    int e = (i*256 + tid)*8;
    __builtin_amdgcn_global_load_lds(
      (const __attribute__((address_space(1))) unsigned int*)(WrF + e),
      (__attribute__((address_space(3))) unsigned int*)&Bs[0][e], 16, 0, 0);
  }

  for (int p=0; p<32; ++p){
    __syncthreads();   // drains stage of Bs[p&1]; all waves done reading Bs[1-(p&1)]
    if (p < 31){
      const unsigned short* src = WrF + (size_t)(p+1)*16384;
      unsigned short* dst = Bs[(p+1)&1];
      #pragma unroll
      for (int i=0;i<8;i++){
        int e = (i*256 + tid)*8;
        __builtin_amdgcn_global_load_lds(
          (const __attribute__((address_space(1))) unsigned int*)(src + e),
          (__attribute__((address_space(3))) unsigned int*)(dst + e), 16, 0, 0);
      }
    }
    const unsigned short* b0 = &Bs[p&1][lane*8];   // n-block 2p
    const unsigned short* b1 = b0 + 8192;          // n-block 2p+1
    f32x4 c0a={0.f,0.f,0.f,0.f}, c0b={0.f,0.f,0.f,0.f};
    f32x4 c1a={0.f,0.f,0.f,0.f}, c1b={0.f,0.f,0.f,0.f};
    #pragma unroll
    for (int f=0; f<16; f+=2){
      bf16x8 x0 = ld_frag(b0 + f*512), y0 = ld_frag(b0 + f*512 + 512);
      bf16x8 x1 = ld_frag(b1 + f*512), y1 = ld_frag(b1 + f*512 + 512);
      c0a = __builtin_amdgcn_mfma_f32_16x16x32_bf16(a[f],   x0, c0a, 0,0,0);
      c1a = __builtin_amdgcn_mfma_f32_16x16x32_bf16(a[f],   x1, c1a, 0,0,0);
      c0b = __builtin_amdgcn_mfma_f32_16x16x32_bf16(a[f+1], y0, c0b, 0,0,0);
      c1b = __builtin_amdgcn_mfma_f32_16x16x32_bf16(a[f+1], y1, c1b, 0,0,0);
    }
    int col0 = p*32 + cr, col1 = col0 + 16;
    float v0 = vW[col0], v1 = vW[col1];
    #pragma unroll
    for (int rg=0; rg<4; rg++){
      float t0 = c0a[rg] + c0b[rg] + decfea[dfo[rg] + col0];
      float t1 = c1a[rg] + c1b[rg] + decfea[dfo[rg] + col1];
      sa[rg] += fast_tanh(t0)*v0 + fast_tanh(t1)*v1;
    }
  }
  // reduce over the 16 n-lanes (cr); lanes cr==0 store their 4 rows
  #pragma unroll
  for (int rg=0; rg<4; rg++){
    float v = sa[rg];
    v += __shfl_xor(v, 1); v += __shfl_xor(v, 2);
    v += __shfl_xor(v, 4); v += __shfl_xor(v, 8);
    sa[rg] = v;
  }
  if (cr == 0){
    #pragma unroll
    for (int rg=0; rg<4; rg++)
      ws[WS_SCORES2 + m0 + cq*4 + rg] = clampf(sa[rg], -64.f, 64.f);
  }
}

// K5: both softmaxes over t
__global__ __launch_bounds__(256) void k_softmax(const float* __restrict__ mask,
    const float* __restrict__ covin, float* __restrict__ ws,
    float* __restrict__ out){
  __shared__ float s1[400], s2[400], mk[400], red[256];
  int b = blockIdx.x, tid = threadIdx.x;
  for (int i=tid;i<400;i+=256){
    s1[i]=ws[WS_SCORES+b*400+i]; s2[i]=ws[WS_SCORES2+b*400+i]; mk[i]=mask[b*400+i];
  }
  __syncthreads();
  float lm = -1e30f;
  for (int i=tid;i<400;i+=256) lm = fmaxf(lm, s1[i]);
  red[tid]=lm; __syncthreads();
  for (int off=128;off>0;off>>=1){ if (tid<off) red[tid]=fmaxf(red[tid],red[tid+off]); __syncthreads(); }
  float mx1 = red[0]; __syncthreads();
  float ls=0.f;
  for (int i=tid;i<400;i+=256){ float e=__expf(s1[i]-mx1); s1[i]=e; ls+=e; }
  red[tid]=ls; __syncthreads();
  for (int off=128;off>0;off>>=1){ if (tid<off) red[tid]+=red[tid+off]; __syncthreads(); }
  float sum1 = red[0]; __syncthreads();
  float la=0.f;
  for (int i=tid;i<400;i+=256){ float a=(s1[i]/sum1)*mk[i]; s1[i]=a; la+=a; }
  red[tid]=la; __syncthreads();
  for (int off=128;off>0;off>>=1){ if (tid<off) red[tid]+=red[tid+off]; __syncthreads(); }
  float sumA = red[0]; __syncthreads();
  for (int i=tid;i<400;i+=256){
    float attn = s1[i]/sumA;
    ws[WS_ATTN + b*400 + i] = attn;
    out[OUT_ATTN + b*400 + i] = attn;
    out[OUT_COV  + b*400 + i] = covin[b*400+i] + attn;
  }
  float lm2 = -1e30f;
  for (int i=tid;i<400;i+=256) lm2 = fmaxf(lm2, s2[i]);
  red[tid]=lm2; __syncthreads();
  for (int off=128;off>0;off>>=1){ if (tid<off) red[tid]=fmaxf(red[tid],red[tid+off]); __syncthreads(); }
  float mx2 = red[0]; __syncthreads();
  float ls2=0.f;
  for (int i=tid;i<400;i+=256){ float e=__expf(s2[i]-mx2); s2[i]=e; ls2+=e; }
  red[tid]=ls2; __syncthreads();
  for (int off=128;off>0;off>>=1){ if (tid<off) red[tid]+=red[tid+off]; __syncthreads(); }
  float sum2 = red[0]; __syncthreads();
  for (int i=tid;i<400;i+=256) ws[WS_ASTRUCT + b*400 + i] = (s2[i]/sum2)*mk[i];
}

// K6: context partials, t-split x4 for memory-level parallelism. grid (64,4,4).
__global__ __launch_bounds__(256) void k_context(const float* __restrict__ eo,
    const float* __restrict__ ws, float* __restrict__ outp){
  __shared__ float at[100], as2[100];
  int b = blockIdx.x, tid = threadIdx.x;
  int n = blockIdx.y*256 + tid;
  int tz = blockIdx.z;
  for (int i=tid;i<100;i+=256){
    at[i]  = ws[WS_ATTN    + b*400 + tz*100 + i];
    as2[i] = ws[WS_ASTRUCT + b*400 + tz*100 + i];
  }
  __syncthreads();
  const float* p = eo + (size_t)b*400*1024 + (size_t)tz*100*1024 + n;
  float a1=0.f, a2=0.f;
  #pragma unroll 4
  for (int t=0;t<100;t++){
    float e = p[(size_t)t*1024];
    a1 += at[t]*e; a2 += as2[t]*e;
  }
  outp[CTX_CT + tz*65536 + b*1024 + n] = a1;
  outp[CTX_CS + tz*65536 + b*1024 + n] = a2;
}

// K6b: combine the 4 t-partials -> c_t (out) and c_struct (ws)
__global__ __launch_bounds__(256) void k_ctxsum(float* __restrict__ ws,
    float* __restrict__ out){
  int b = blockIdx.x, tid = threadIdx.x;
  int n = tid*4;
  float4 ct = {0.f,0.f,0.f,0.f}, cs = {0.f,0.f,0.f,0.f};
  #pragma unroll
  for (int tz=0;tz<4;tz++){
    float4 a = *(const float4*)(out + CTX_CT + tz*65536 + b*1024 + n);
    float4 c = *(const float4*)(out + CTX_CS + tz*65536 + b*1024 + n);
    ct.x+=a.x; ct.y+=a.y; ct.z+=a.z; ct.w+=a.w;
    cs.x+=c.x; cs.y+=c.y; cs.z+=c.z; cs.w+=c.w;
  }
  *(float4*)(out + OUT_CT + b*1024 + n) = ct;
  *(float4*)(ws + WS_CSTRUCT + b*1024 + n) = cs;
}

// K7: p_gen = sigmoid(pg_W . [c_struct, s_t_hat, x] + pg_b)
__global__ __launch_bounds__(256) void k_pgen(const float* __restrict__ pgW,
    const float* __restrict__ pgb, float* __restrict__ ws,
    float* __restrict__ out){
  __shared__ float red[256];
  int b=blockIdx.x, tid=threadIdx.x;
  float a=0.f;
  for (int i=tid;i<2176;i+=256){
    float x;
    if (i<1024)      x = ws[WS_CSTRUCT + b*1024 + i];
    else if (i<2048) x = ws[WS_STHAT   + b*1024 + (i-1024)];
    else             x = ws[WS_X       + b*128  + (i-2048)];
    a += x * pgW[i];
  }
  red[tid]=a; __syncthreads();
  for (int off=128;off>0;off>>=1){ if(tid<off) red[tid]+=red[tid+off]; __syncthreads(); }
  if (tid==0){
    float p = sigm(red[0] + pgb[0]);
    ws[WS_PGEN+b]=p; out[OUT_PGEN+b]=p;
  }
}

// K8: out1 = o1_W @ [h_new, c_struct] + o1_b  (wave-per-output, lane-split-K;
// stored bf16 for the o2 MFMA GEMM)
__global__ __launch_bounds__(256) void k_out1(const float* __restrict__ o1W,
    const float* __restrict__ o1b, float* __restrict__ ws){
  __shared__ float in1[1536];
  int b=blockIdx.x, q=blockIdx.y, tid=threadIdx.x;
  for (int i=tid;i<512;i+=256)  in1[i]     = ws[WS_H + b*512 + i];
  for (int i=tid;i<1024;i+=256) in1[512+i] = ws[WS_CSTRUCT + b*1024 + i];
  __syncthreads();
  int wave = tid>>6, lane = tid&63;
  for (int oo=0; oo<64; ++oo){
    int o = q*256 + wave*64 + oo;
    const float* row = o1W + (size_t)o*1536;
    float acc = 0.f;
    #pragma unroll
    for (int i=0;i<24;i++) acc += row[lane + 64*i] * in1[lane + 64*i];
    for (int off=32; off>0; off>>=1) acc += __shfl_down(acc, off);
    if (lane==0) ((unsigned short*)(ws + WS_OUT1BF))[b*512 + o] = f2b(o1b[o] + acc);
  }
}

// K9: logits = out1 @ o2_W.T + o2_b  (M=64, N=50000, K=512); f32 logits staged in d_out
__global__ __launch_bounds__(256) void k_o2(float* __restrict__ ws,
    const float* __restrict__ o2W, const float* __restrict__ o2b,
    float* __restrict__ out){
  __shared__ __align__(16) unsigned short As[64][72];
  __shared__ __align__(16) unsigned short Bs[64][72];
  int tid=threadIdx.x;
  int n0 = blockIdx.x*64;
  int lane=tid&63, wave=tid>>6, wm=wave&1, wn=wave>>1;
  int lrow=tid>>2, lcol=(tid&3)*16;
  const unsigned short* out1 = (const unsigned short*)(ws + WS_OUT1BF);
  f32x4 acc00={0.f,0.f,0.f,0.f}, acc01={0.f,0.f,0.f,0.f};
  f32x4 acc10={0.f,0.f,0.f,0.f}, acc11={0.f,0.f,0.f,0.f};
  int nrow = n0 + lrow;
  bool bvalid = nrow < VOCAB;
  int fr = lane & 15, fq = (lane >> 4) * 8;
  for (int kc=0;kc<512;kc+=64){
    u16x8 a0 = *(const u16x8*)(out1 + lrow*512 + kc + lcol);
    u16x8 a1 = *(const u16x8*)(out1 + lrow*512 + kc + lcol + 8);
    u16x8 bb0 = {0,0,0,0,0,0,0,0}, bb1 = {0,0,0,0,0,0,0,0};
    if (bvalid){
      const float4* bp = (const float4*)(o2W + (size_t)nrow*512 + kc + lcol);
      float4 b0=bp[0], b1=bp[1], b2=bp[2], b3=bp[3];
      bb0 = cvt8(b0,b1); bb1 = cvt8(b2,b3);
    }
    __syncthreads();
    *(u16x8*)&As[lrow][lcol] = a0;  *(u16x8*)&As[lrow][lcol+8] = a1;
    *(u16x8*)&Bs[lrow][lcol] = bb0; *(u16x8*)&Bs[lrow][lcol+8] = bb1;
    __syncthreads();
    #pragma unroll
    for (int kk=0; kk<64; kk+=32){
      bf16x8 aA = ld_frag(&As[wm*32 +      fr][kk + fq]);
      bf16x8 aB = ld_frag(&As[wm*32 + 16 + fr][kk + fq]);
      bf16x8 bA = ld_frag(&Bs[wn*32 +      fr][kk + fq]);
      bf16x8 bB = ld_frag(&Bs[wn*32 + 16 + fr][kk + fq]);
      acc00 = __builtin_amdgcn_mfma_f32_16x16x32_bf16(aA, bA, acc00, 0,0,0);
      acc01 = __builtin_amdgcn_mfma_f32_16x16x32_bf16(aA, bB, acc01, 0,0,0);
      acc10 = __builtin_amdgcn_mfma_f32_16x16x32_bf16(aB, bA, acc10, 0,0,0);
      acc11 = __builtin_amdgcn_mfma_f32_16x16x32_bf16(aB, bB, acc11, 0,0,0);
    }
  }
  int cq=lane>>4, cr=lane&15;
  #pragma unroll
  for (int i=0;i<2;i++){
    #pragma unroll
    for (int rg=0;rg<4;rg++){
      int row = wm*32 + i*16 + cq*4 + rg;   // batch row (0..63)
      int n1 = n0 + wn*32 + cr, n2 = n1+16;
      float v1 = (i==0?acc00[rg]:acc10[rg]);
      float v2 = (i==0?acc01[rg]:acc11[rg]);
      if (n1 < VOCAB) out[(size_t)row*VEXT + n1] = clampf(v1 + o2b[n1], -80.f, 80.f);
      if (n2 < VOCAB) out[(size_t)row*VEXT + n2] = clampf(v2 + o2b[n2], -80.f, 80.f);
    }
  }
}

// K10a: vocab-softmax stats, 8-way n-split. grid (64,8): partial max + expsum
// (local-max form) per 6250-elem slice -> ws partials.
__global__ __launch_bounds__(256) void k_vsm_part(const float* __restrict__ out,
    float* __restrict__ ws){
  __shared__ float red[256];
  int b=blockIdx.x, s=blockIdx.y, tid=threadIdx.x;
  const float* lg = out + (size_t)b*VEXT + s*6250;
  float lm=-1e30f;
  for (int i=tid;i<6250;i+=256) lm=fmaxf(lm, lg[i]);
  red[tid]=lm; __syncthreads();
  for (int off=128;off>0;off>>=1){ if(tid<off) red[tid]=fmaxf(red[tid],red[tid+off]); __syncthreads(); }
  float mx=red[0]; __syncthreads();
  float sm=0.f;
  for (int i=tid;i<6250;i+=256) sm+=__expf(lg[i]-mx);
  red[tid]=sm; __syncthreads();
  for (int off=128;off>0;off>>=1){ if(tid<off) red[tid]+=red[tid+off]; __syncthreads(); }
  if (tid==0){ ws[WS_PMAX + b*8 + s]=mx; ws[WS_PSUM + b*8 + s]=red[0]; }
}

// K10a': combine 8 partials per row -> (rowmax, rowsum) with rescale (exact)
__global__ __launch_bounds__(64) void k_vsm_comb(float* __restrict__ ws){
  int b = blockIdx.x;
  if (threadIdx.x==0){
    float M=-1e30f;
    for (int s=0;s<8;s++) M=fmaxf(M, ws[WS_PMAX + b*8 + s]);
    float S=0.f;
    for (int s=0;s<8;s++) S += __expf(ws[WS_PMAX + b*8 + s]-M)*ws[WS_PSUM + b*8 + s];
    ws[WS_ROWMAX+b]=M; ws[WS_ROWSUM+b]=S;
  }
}

// K10b: in-place  out <- p_gen * softmax(logits); zero the OOV tail
__global__ __launch_bounds__(256) void k_vsm_write(const float* __restrict__ ws,
    float* __restrict__ out){
  int b=blockIdx.y;
  int i=blockIdx.x*256+threadIdx.x;
  if (i>=VEXT) return;
  float* p = out + (size_t)b*VEXT + i;
  if (i<VOCAB) *p = ws[WS_PGEN+b]*__expf(*p - ws[WS_ROWMAX+b])/ws[WS_ROWSUM+b];
  else         *p = 0.f;
}

// K10c: scatter-add (1-p_gen)*attn at extended-vocab indices (plain f32 atomics)
__global__ __launch_bounds__(256) void k_scatter(const int* __restrict__ ebev,
    const float* __restrict__ ws, float* __restrict__ out){
  int idx = blockIdx.x*256+threadIdx.x;  // 25600 total
  int b = idx/400;
  float add = (1.f - ws[WS_PGEN+b]) * ws[WS_ATTN+idx];
  int v = ebev[idx];
  atomicAdd(out + (size_t)b*VEXT + v, add);
}

extern "C" void kernel_launch(void* const* d_in, const int* in_sizes, int n_in,
                              void* d_out, int out_size, void* d_ws, size_t ws_size,
                              hipStream_t stream){
  (void)in_sizes; (void)n_in; (void)out_size; (void)ws_size;
  const int*   y_t_1   = (const int*)d_in[0];
  const float* s_h     = (const float*)d_in[1];
  const float* s_c     = (const float*)d_in[2];
  const float* enc_out = (const float*)d_in[3];
  const float* enc_ft  = (const float*)d_in[4];
  const float* mask    = (const float*)d_in[5];
  const float* c_t_1   = (const float*)d_in[6];
  const int*   ebev    = (const int*)d_in[8];
  const float* cover   = (const float*)d_in[9];
  const float* ri      = (const float*)d_in[11];
  const float* embW    = (const float*)d_in[12];
  const float* WsW     = (const float*)d_in[13];
  const float* Wsb     = (const float*)d_in[14];
  const float* vW      = (const float*)d_in[15];
  const float* WcW     = (const float*)d_in[16];
  const float* WrW     = (const float*)d_in[17];
  const float* xcW     = (const float*)d_in[18];
  const float* xcb     = (const float*)d_in[19];
  const float* Wih     = (const float*)d_in[20];
  const float* Whh     = (const float*)d_in[21];
  const float* bih     = (const float*)d_in[22];
  const float* bhh     = (const float*)d_in[23];
  const float* pgW     = (const float*)d_in[24];
  const float* pgb     = (const float*)d_in[25];
  const float* o1W     = (const float*)d_in[26];
  const float* o1b     = (const float*)d_in[27];
  const float* o2W     = (const float*)d_in[28];
  const float* o2b     = (const float*)d_in[29];
  float* ws  = (float*)d_ws;
  float* out = (float*)d_out;
  float* gates = out;   // scratch inside OUT_FINAL region, overwritten by k_o2/k_vsm_write
  unsigned short* Wr16 = (unsigned short*)(out + OUT_WR16);

  k_wrcvt   <<<256,           256,0,stream>>>(WrW, Wr16);
  k_embx    <<<dim3(BATCH,4), 256,0,stream>>>(y_t_1, embW, c_t_1, xcW, xcb, ws);
  k_gates   <<<dim3(BATCH,16),256,0,stream>>>(Wih, Whh, bih, bhh, s_h, ws, gates);
  k_lstmpt  <<<BATCH,         256,0,stream>>>(gates, s_c, ws, out+OUT_H, out+OUT_C);
  k_decfea  <<<dim3(BATCH,4), 256,0,stream>>>(WsW, Wsb, ws);
  k_scores1 <<<dim3(BATCH,100),256,0,stream>>>(enc_ft, cover, vW, WcW, ws);
  k_scores2 <<<400,           256,0,stream>>>(ri, Wr16, vW, ws);
  k_softmax <<<BATCH,         256,0,stream>>>(mask, cover, ws, out);
  k_context <<<dim3(BATCH,4,4),256,0,stream>>>(enc_out, ws, out);
  k_ctxsum  <<<BATCH,         256,0,stream>>>(ws, out);
  k_pgen    <<<BATCH,         256,0,stream>>>(pgW, pgb, ws, out);
  k_out1    <<<dim3(BATCH,2), 256,0,stream>>>(o1W, o1b, ws);
  k_o2      <<<782,           256,0,stream>>>(ws, o2W, o2b, out);
  k_vsm_part<<<dim3(BATCH,8), 256,0,stream>>>(out, ws);
  k_vsm_comb<<<BATCH,         64, 0,stream>>>(ws);
  k_vsm_write<<<dim3(196,BATCH),256,0,stream>>>(ws, out);
  k_scatter <<<100,           256,0,stream>>>(ebev, ws, out);
}